// Round 13
// baseline (265.964 us; speedup 1.0000x reference)
//
#include <hip/hip_runtime.h>
#include <hip/hip_bf16.h>
#include <cstdint>

// Problem constants
constexpr int Bb = 8, Cc = 256, Hh = 64, Ww = 64, Nn = 4096;
constexpr int KD = 128, VD = 256, HP = 66; // HP = padded spatial (64+2)

typedef __attribute__((ext_vector_type(8))) short short8_t;   // 8 bf16 (4 VGPR) MFMA frag
typedef __attribute__((ext_vector_type(4))) short shortx4;    // 4 bf16 packed store
typedef __attribute__((ext_vector_type(4))) float floatx4;    // MFMA accumulator

// kScale = log2(e)/sqrt(128). Softmax column factor exp2(-kScale*sq_j) cancels
// in normalization -> P' = exp2(2*kScale*dot - kScale*sq_i), out = V P'/colsum.
constexpr float kScale = 0.08838834764831845f * 1.4426950408889634f;
constexpr float kTwoK  = 2.0f * kScale;

static __device__ __forceinline__ ushort f2bf(float f) {
    union { float f; uint32_t u; } v{f};
    uint32_t r = v.u + 0x7FFFu + ((v.u >> 16) & 1u);  // RNE
    return (ushort)(r >> 16);
}
static __device__ __forceinline__ float bf2f(ushort b) {
    union { uint32_t u; float f; } v{(uint32_t)b << 16};
    return v.f;
}
// pack two f32 -> two bf16 in one u32 (RNE), single HW inst
static __device__ __forceinline__ uint32_t pk_bf16(float a, float b) {
    uint32_t r;
    asm("v_cvt_pk_bf16_f32 %0, %1, %2" : "=v"(r) : "v"(a), "v"(b));
    return r;
}
// raw v_exp_f32 (2^x) — args here are in [-126, 6]; no libm range handling
static __device__ __forceinline__ float exp2_raw(float x) {
    float r;
    asm("v_exp_f32 %0, %1" : "=v"(r) : "v"(x));
    return r;
}

// async global->LDS, 16B per lane; lds base must be wave-uniform (HW adds lane*16)
static __device__ __forceinline__ void gload_lds16(const void* g, void* l) {
    __builtin_amdgcn_global_load_lds((const __attribute__((address_space(1))) uint32_t*)g,
                                     (__attribute__((address_space(3))) uint32_t*)l, 16, 0, 0);
}

// ---------------------------------------------------------------------------
// K1: x[b][c][y][x] (f32) -> xpad[b][y+1][x+1][c] (bf16, channel-last).
__global__ __launch_bounds__(256) void pad_transpose(const float* __restrict__ x,
                                                     ushort* __restrict__ xpad) {
    int bid = blockIdx.x;
    int b = bid & 7, rest = bid >> 3;
    int y = rest & 63, cg = rest >> 6;   // cg: 64-channel group
    int t = threadIdx.x;
    __shared__ float tile[64][65];
    int xcol = t & 63;
    int crow = t >> 6;  // 0..3
    const float* xb = x + ((size_t)(b * Cc + cg * 64) * Nn) + y * 64;
#pragma unroll
    for (int i = 0; i < 16; i++) {
        int c = crow + i * 4;
        tile[c][xcol] = xb[(size_t)c * Nn + xcol];
    }
    __syncthreads();
    int c = t & 63;
    int x4 = t >> 6;
    ushort* dst = xpad + (((size_t)(b * HP + (y + 1)) * HP) + 1) * Cc + cg * 64 + c;
#pragma unroll
    for (int i = 0; i < 16; i++) {
        int xx = x4 + i * 4;
        dst[(size_t)xx * Cc] = f2bf(tile[c][xx]);
    }
}

// ---------------------------------------------------------------------------
// K2: repack weights w[oc][c][3][3] (f32) -> wt[r][oc][c] (bf16), r = dy*3+dx
__global__ __launch_bounds__(256) void repack_w(const float* __restrict__ kw,
                                                const float* __restrict__ vw,
                                                ushort* __restrict__ wtk,
                                                ushort* __restrict__ wtv) {
    int idx = blockIdx.x * 256 + threadIdx.x;
    const int nk = KD * Cc;   // 32768
    const int nv = VD * Cc;   // 65536
    if (idx < nk) {
        const float* src = kw + (size_t)idx * 9;
        int oc = idx / Cc, c = idx % Cc;
#pragma unroll
        for (int r = 0; r < 9; r++) wtk[((size_t)r * KD + oc) * Cc + c] = f2bf(src[r]);
    } else if (idx < nk + nv) {
        int j = idx - nk;
        const float* src = vw + (size_t)j * 9;
        int oc = j / Cc, c = j % Cc;
#pragma unroll
        for (int r = 0; r < 9; r++) wtv[((size_t)r * VD + oc) * Cc + c] = f2bf(src[r]);
    }
}

// ---------------------------------------------------------------------------
// K3: implicit-GEMM conv3x3, weight slab LDS-staged, TWO image rows per block:
// each staged afr read feeds 2 MFMAs (rows y0, y0+1) -> LDS reads per unit
// work halved vs round-12 (conv was read-bound like attn).
template <int MODE, int OC>
__global__ __launch_bounds__(256) void conv_gemm(const ushort* __restrict__ xpad,
                                                 const ushort* __restrict__ wt,
                                                 const float* __restrict__ bias,
                                                 ushort* __restrict__ kt_out,
                                                 float* __restrict__ f32_out,
                                                 ushort* __restrict__ vb_out) {
    int bid = blockIdx.x;
    int b = bid & 7;
    int ocg, y0;
    if (OC == 128) { ocg = 0; y0 = (bid >> 3) * 2; }            // 256 blocks
    else           { ocg = (bid >> 3) & 1; y0 = (bid >> 4) * 2; } // 512 blocks
    int lane = threadIdx.x & 63, wv = threadIdx.x >> 6;
    int l15 = lane & 15, g = lane >> 4;
    int oc0 = ocg * 128;
    const int swzA = l15 & 7;

    __shared__ ushort wslab[2][128 * 128];   // 2 x 32KB weight half-slabs

    size_t wsoff[8];
    int ldsrow[8];
#pragma unroll
    for (int h = 0; h < 8; h++) {
        int row = wv * 32 + h * 4 + (lane >> 4);      // oc row this lane stages
        wsoff[h] = (size_t)row * Cc + (((lane & 15) ^ (row & 7)) * 8);
        ldsrow[h] = (wv * 32 + h * 4) * 128;
    }

    floatx4 acc[8][2];
#pragma unroll
    for (int m = 0; m < 8; m++)
#pragma unroll
        for (int rr = 0; rr < 2; rr++) acc[m][rr] = (floatx4){0.f, 0.f, 0.f, 0.f};

    const ushort* xb = xpad + ((size_t)b * HP * HP) * Cc;
    int xcol = wv * 16 + l15;  // output x position (wave's 16 columns)

    auto stage = [&](int hs, int bi) {
        int r = hs >> 1, hc = hs & 1;
        const ushort* wb = wt + ((size_t)r * OC + oc0) * Cc + hc * 128;
#pragma unroll
        for (int h = 0; h < 8; h++)
            gload_lds16(wb + wsoff[h], &wslab[bi][ldsrow[h]]);
    };

    stage(0, 0);
    __syncthreads();   // implicit vmcnt(0): slab 0 resident

#pragma unroll 1
    for (int hs = 0; hs < 18; ++hs) {
        int bi = hs & 1;
        if (hs < 17) stage(hs + 1, bi ^ 1);   // prefetch; drained by end barrier

        int r = hs >> 1, hc = hs & 1;
        int dy = r / 3, dx = r % 3;
        const ushort* bsrc0 = xb + ((size_t)(y0 + dy) * HP + xcol + dx) * Cc + hc * 128 + g * 8;
        const ushort* bsrc1 = bsrc0 + (size_t)HP * Cc;   // row y0+1
#pragma unroll
        for (int cc = 0; cc < 4; cc++) {      // 4 k-steps of 32 channels
            short8_t bfragA = *(const short8_t*)(bsrc0 + cc * 32);
            short8_t bfragB = *(const short8_t*)(bsrc1 + cc * 32);
#pragma unroll
            for (int m = 0; m < 8; m++) {
                short8_t afrag = *(const short8_t*)&wslab[bi][(m * 16 + l15) * 128 + ((cc * 4 + g) ^ swzA) * 8];
                acc[m][0] = __builtin_amdgcn_mfma_f32_16x16x32_bf16(afrag, bfragA, acc[m][0], 0, 0, 0);
                acc[m][1] = __builtin_amdgcn_mfma_f32_16x16x32_bf16(afrag, bfragB, acc[m][1], 0, 0, 0);
            }
        }
        __syncthreads();   // reads done + prefetch drained
    }

#pragma unroll
    for (int rr = 0; rr < 2; rr++) {
        int pos = (y0 + rr) * 64 + xcol;
        if (MODE == 0) {
            ushort* kt = kt_out + ((size_t)(b * Nn + pos)) * KD;
#pragma unroll
            for (int m = 0; m < 8; m++) {
                floatx4 bv = *(const floatx4*)(bias + m * 16 + g * 4);
                shortx4 pk;
#pragma unroll
                for (int r = 0; r < 4; r++) pk[r] = (short)f2bf(acc[m][rr][r] + bv[r]);
                *(shortx4*)(kt + m * 16 + g * 4) = pk;
            }
        } else {
#pragma unroll
            for (int m = 0; m < 8; m++) {
                floatx4 bv = *(const floatx4*)(bias + oc0 + m * 16 + g * 4);
#pragma unroll
                for (int r = 0; r < 4; r++) {
                    int oc = oc0 + m * 16 + g * 4 + r;
                    float v = acc[m][rr][r] + bv[r];
                    f32_out[((size_t)(b * 512 + oc)) * Nn + pos] = v;       // d_out f32
                    vb_out[((size_t)(b * VD + oc)) * Nn + pos] = f2bf(v);   // bf16 for PV
                }
            }
        }
    }
}

// ---------------------------------------------------------------------------
// K4: sq2[b*N+pos] = kScale * sum_ch Kt[pos][ch]^2 (scale pre-folded for attn).
__global__ __launch_bounds__(256) void sq_kernel(const ushort* __restrict__ kt,
                                                 float* __restrict__ sq) {
    int bid = blockIdx.x;
    int idx = (bid & 7) * Nn + (bid >> 3) * 256 + threadIdx.x;
    const ushort* src = kt + (size_t)idx * KD;
    float s = 0.f;
#pragma unroll
    for (int i = 0; i < 16; i++) {
        short8_t v = *(const short8_t*)(src + i * 8);
#pragma unroll
        for (int e = 0; e < 8; e++) {
            float f = bf2f((ushort)v[e]);
            s += f * f;
        }
    }
    sq[idx] = s * kScale;
}

// ---------------------------------------------------------------------------
// K5: fused attention — r12 (PV vd/j-split) with HALF-SIZE pt: P^T is written
// one k2-half (32 i) at a time, reused between the two PV sub-phases.
// LDS: bufK 16K + bufV 32K + pt 5K = 54272B -> 3 blocks/CU (was 2) = 3
// waves/SIMD of latency hiding. Cost: 4 barriers/iter instead of 2.
// dls overlays dead pt after the loop (512B-granularity fit for 3 blocks).
__global__ __launch_bounds__(256) void attn_kernel(const ushort* __restrict__ kt,
                                                   const ushort* __restrict__ vb,
                                                   const float* __restrict__ sq2,
                                                   float* __restrict__ out) {
    int bid = blockIdx.x;
    int b = bid & 7, jt = bid >> 3;
    int lane = threadIdx.x & 63, wv = threadIdx.x >> 6;
    int l15 = lane & 15, g = lane >> 4;

    __shared__ ushort bufK[64 * 128];      // 16KB: [i-row][swizzled 16B units]
    __shared__ ushort bufV[256 * 64];      // 32KB: [vd][swizzled 16B units]
    __shared__ ushort pt[4][16][40];       // 5KB: per-wave P^T half-tile [j][i0..31+pad]

    const ushort* ktb = kt + ((size_t)b * Nn) * KD;
    const ushort* vbb = vb + ((size_t)b * VD) * Nn;
    const float* sqb = sq2 + b * Nn;

    // per-lane staging source pointers (it=0); LDS dests are wave-uniform
    const ushort* skp[4];
#pragma unroll
    for (int h = 0; h < 4; h++) {
        int row = wv * 16 + h * 4 + (lane >> 4);
        skp[h] = ktb + (size_t)row * KD + (((lane & 15) ^ (row & 7)) * 8);
    }
    const ushort* svp[8];
#pragma unroll
    for (int h = 0; h < 8; h++) {
        int vd = wv * 64 + h * 8 + (lane >> 3);
        svp[h] = vbb + (size_t)vd * Nn + (((lane & 7) ^ (vd & 7)) * 8);
    }

    // kj B-frags for this wave's 16 j columns (S-phase ownership)
    int j = jt * 64 + wv * 16 + l15;
    short8_t kj[4];
#pragma unroll
    for (int kk = 0; kk < 4; kk++)
        kj[kk] = *(const short8_t*)(ktb + (size_t)j * KD + kk * 32 + g * 8);

    // PV ownership: vd-half vh = wv>>1, j-half jh = wv&1
    const int vh = wv >> 1, jh = wv & 1;

    floatx4 acc[8][2];   // [m: vd-tile within half][s: j-sub within half]
#pragma unroll
    for (int m = 0; m < 8; m++)
#pragma unroll
        for (int s = 0; s < 2; s++) acc[m][s] = (floatx4){0.f, 0.f, 0.f, 0.f};
    float dsum = 0.f;
    const int swzA = l15 & 7;

    // prologue: stage K(0), V(0)
#pragma unroll
    for (int h = 0; h < 4; h++) gload_lds16(skp[h], &bufK[(wv * 16 + h * 4) * 128]);
#pragma unroll
    for (int h = 0; h < 8; h++) gload_lds16(svp[h], &bufV[(wv * 64 + h * 8) * 64]);
    __syncthreads();   // implicit vmcnt(0): both tiles resident

#pragma unroll 1
    for (int it = 0; it < 64; ++it) {
        int i0 = it * 64;

        // S-phase: all 4 i-subtiles (16 afr reads, 16 MFMAs)
        floatx4 sacc[4];
#pragma unroll
        for (int f = 0; f < 4; f++) sacc[f] = (floatx4){0.f, 0.f, 0.f, 0.f};
#pragma unroll
        for (int kk = 0; kk < 4; kk++) {
#pragma unroll
            for (int f = 0; f < 4; f++) {
                short8_t afr = *(const short8_t*)&bufK[(f * 16 + l15) * 128 + ((kk * 4 + g) ^ swzA) * 8];
                sacc[f] = __builtin_amdgcn_mfma_f32_16x16x32_bf16(afr, kj[kk], sacc[f], 0, 0, 0);
            }
        }
        // transform f=0,1 -> pt half (i-local 0..31)
#pragma unroll
        for (int f = 0; f < 2; f++) {
            floatx4 sqi = *(const floatx4*)(sqb + i0 + f * 16 + g * 4);
            float p0 = exp2_raw(sacc[f][0] * kTwoK - sqi[0]);
            float p1 = exp2_raw(sacc[f][1] * kTwoK - sqi[1]);
            float p2 = exp2_raw(sacc[f][2] * kTwoK - sqi[2]);
            float p3 = exp2_raw(sacc[f][3] * kTwoK - sqi[3]);
            dsum += (p0 + p1) + (p2 + p3);
            uint2 w2 = {pk_bf16(p0, p1), pk_bf16(p2, p3)};
            *(uint2*)&pt[wv][l15][f * 16 + g * 4] = w2;
        }
        __syncthreads();   // sync_a: pt(k2=0) visible; bufK reads done

        // K(it+1) prefetch (WAR-safe; drains at sync_b)
        if (it < 63) {
#pragma unroll
            for (int h = 0; h < 4; h++)
                gload_lds16(skp[h] + (size_t)(i0 + 64) * KD, &bufK[(wv * 16 + h * 4) * 128]);
        }

        // PV k2=0: vd-half vh, j-half jh
        {
            short8_t pfr[2];
#pragma unroll
            for (int s = 0; s < 2; s++)
                pfr[s] = *(const short8_t*)&pt[jh * 2 + s][l15][g * 8];
#pragma unroll
            for (int m = 0; m < 8; m++) {
                int row = vh * 128 + m * 16 + l15;
                short8_t vfr = *(const short8_t*)&bufV[row * 64 + ((0 * 4 + g) ^ swzA) * 8];
#pragma unroll
                for (int s = 0; s < 2; s++)
                    acc[m][s] = __builtin_amdgcn_mfma_f32_16x16x32_bf16(vfr, pfr[s], acc[m][s], 0, 0, 0);
            }
        }
        __syncthreads();   // sync_b: pt(k2=0) reads done (safe to overwrite)

        // transform f=2,3 -> pt half (i-local 32..63 stored in same slots)
#pragma unroll
        for (int f = 2; f < 4; f++) {
            floatx4 sqi = *(const floatx4*)(sqb + i0 + f * 16 + g * 4);
            float p0 = exp2_raw(sacc[f][0] * kTwoK - sqi[0]);
            float p1 = exp2_raw(sacc[f][1] * kTwoK - sqi[1]);
            float p2 = exp2_raw(sacc[f][2] * kTwoK - sqi[2]);
            float p3 = exp2_raw(sacc[f][3] * kTwoK - sqi[3]);
            dsum += (p0 + p1) + (p2 + p3);
            uint2 w2 = {pk_bf16(p0, p1), pk_bf16(p2, p3)};
            *(uint2*)&pt[wv][l15][(f - 2) * 16 + g * 4] = w2;
        }
        __syncthreads();   // sync_c: pt(k2=1) visible

        // PV k2=1
        {
            short8_t pfr[2];
#pragma unroll
            for (int s = 0; s < 2; s++)
                pfr[s] = *(const short8_t*)&pt[jh * 2 + s][l15][g * 8];
#pragma unroll
            for (int m = 0; m < 8; m++) {
                int row = vh * 128 + m * 16 + l15;
                short8_t vfr = *(const short8_t*)&bufV[row * 64 + ((1 * 4 + g) ^ swzA) * 8];
#pragma unroll
                for (int s = 0; s < 2; s++)
                    acc[m][s] = __builtin_amdgcn_mfma_f32_16x16x32_bf16(vfr, pfr[s], acc[m][s], 0, 0, 0);
            }
        }
        __syncthreads();   // sync_d: bufV/pt reads done; K prefetch long drained

        // V(it+1) prefetch (drains at next iter's sync_a)
        if (it < 63) {
#pragma unroll
            for (int h = 0; h < 8; h++)
                gload_lds16(svp[h] + (i0 + 64), &bufV[(wv * 64 + h * 8) * 64]);
        }
    }

    // dsum for this wave's S-columns: reduce across g-slices, exchange via
    // dls overlaid on dead pt (all pt reads completed at last sync_d).
    dsum += __shfl_xor(dsum, 16, 64);
    dsum += __shfl_xor(dsum, 32, 64);
    float* dls = (float*)&pt[0][0][0];
    if (g == 0) dls[wv * 16 + l15] = dsum;
    __syncthreads();
    float rden[2];
#pragma unroll
    for (int s = 0; s < 2; s++) rden[s] = 1.f / dls[(jh * 2 + s) * 16 + l15];

    // output: vd = vh*128 + m*16 + g*4 + r, j = jt*64 + jh*32 + s*16 + l15
    float* ob = out + ((size_t)(b * 512 + 256 + vh * 128)) * Nn + jt * 64 + jh * 32 + l15;
#pragma unroll
    for (int m = 0; m < 8; m++) {
#pragma unroll
        for (int s = 0; s < 2; s++) {
#pragma unroll
            for (int r = 0; r < 4; r++) {
                int vd = m * 16 + g * 4 + r;
                ob[(size_t)vd * Nn + s * 16] = acc[m][s][r] * rden[s];
            }
        }
    }
}

// ---------------------------------------------------------------------------
extern "C" void kernel_launch(void* const* d_in, const int* in_sizes, int n_in,
                              void* d_out, int out_size, void* d_ws, size_t ws_size,
                              hipStream_t stream) {
    const float* x     = (const float*)d_in[0];
    const float* kw    = (const float*)d_in[1];
    const float* kbias = (const float*)d_in[2];
    const float* vw    = (const float*)d_in[3];
    const float* vbias = (const float*)d_in[4];
    float* out = (float*)d_out;  // reference output dtype is FLOAT32
    char* ws = (char*)d_ws;

    // workspace layout (bytes) — total 44,908,544
    constexpr size_t XPAD = 0;                         // 8*66*66*256*2 = 17,842,176
    constexpr size_t WTK  = 17842176;                  // 9*128*256*2   =    589,824
    constexpr size_t WTV  = 18432000;                  // 9*256*256*2   =  1,179,648
    constexpr size_t KT   = 19611648;                  // 8*4096*128*2  =  8,388,608
    constexpr size_t VB   = 28000256;                  // 8*256*4096*2  = 16,777,216
    constexpr size_t SQ   = 44777472;                  // 8*4096*4      =    131,072

    ushort* xpad = (ushort*)(ws + XPAD);
    ushort* wtk  = (ushort*)(ws + WTK);
    ushort* wtv  = (ushort*)(ws + WTV);
    ushort* ktw  = (ushort*)(ws + KT);
    ushort* vbw  = (ushort*)(ws + VB);
    float*  sqw  = (float*)(ws + SQ);

    hipMemsetAsync(xpad, 0, 17842176, stream);  // zero borders of padded input
    pad_transpose<<<dim3(2048), 256, 0, stream>>>(x, xpad);
    repack_w<<<dim3(384), 256, 0, stream>>>(kw, vw, wtk, wtv);
    conv_gemm<0, KD><<<dim3(256), 256, 0, stream>>>(xpad, wtk, kbias, ktw, nullptr, nullptr);
    conv_gemm<1, VD><<<dim3(512), 256, 0, stream>>>(xpad, wtv, vbias, nullptr, out, vbw);
    sq_kernel<<<dim3(128), 256, 0, stream>>>(ktw, sqw);
    attn_kernel<<<dim3(512), 256, 0, stream>>>(ktw, vbw, sqw, out);
}

// Round 14
// 247.511 us; speedup vs baseline: 1.0746x; 1.0746x over previous
//
#include <hip/hip_runtime.h>
#include <hip/hip_bf16.h>
#include <cstdint>

// Problem constants
constexpr int Bb = 8, Cc = 256, Hh = 64, Ww = 64, Nn = 4096;
constexpr int KD = 128, VD = 256, HP = 66; // HP = padded spatial (64+2)

typedef __attribute__((ext_vector_type(8))) short short8_t;   // 8 bf16 (4 VGPR) MFMA frag
typedef __attribute__((ext_vector_type(4))) short shortx4;    // 4 bf16 packed store
typedef __attribute__((ext_vector_type(4))) float floatx4;    // MFMA accumulator

// kScale = log2(e)/sqrt(128). Softmax column factor exp2(-kScale*sq_j) cancels
// in normalization -> P' = exp2(2*kScale*dot - kScale*sq_i), out = V P'/colsum.
constexpr float kScale = 0.08838834764831845f * 1.4426950408889634f;
constexpr float kTwoK  = 2.0f * kScale;

static __device__ __forceinline__ ushort f2bf(float f) {
    union { float f; uint32_t u; } v{f};
    uint32_t r = v.u + 0x7FFFu + ((v.u >> 16) & 1u);  // RNE
    return (ushort)(r >> 16);
}
static __device__ __forceinline__ float bf2f(ushort b) {
    union { uint32_t u; float f; } v{(uint32_t)b << 16};
    return v.f;
}
// pack two f32 -> two bf16 in one u32 (RNE), single HW inst
static __device__ __forceinline__ uint32_t pk_bf16(float a, float b) {
    uint32_t r;
    asm("v_cvt_pk_bf16_f32 %0, %1, %2" : "=v"(r) : "v"(a), "v"(b));
    return r;
}
// raw v_exp_f32 (2^x) — args here are in [-126, 6]; no libm range handling
static __device__ __forceinline__ float exp2_raw(float x) {
    float r;
    asm("v_exp_f32 %0, %1" : "=v"(r) : "v"(x));
    return r;
}

// async global->LDS, 16B per lane; lds base must be wave-uniform (HW adds lane*16)
static __device__ __forceinline__ void gload_lds16(const void* g, void* l) {
    __builtin_amdgcn_global_load_lds((const __attribute__((address_space(1))) uint32_t*)g,
                                     (__attribute__((address_space(3))) uint32_t*)l, 16, 0, 0);
}

// ---------------------------------------------------------------------------
// K1: x[b][c][y][x] (f32) -> xpad[b][y+1][x+1][c] (bf16, channel-last).
__global__ __launch_bounds__(256) void pad_transpose(const float* __restrict__ x,
                                                     ushort* __restrict__ xpad) {
    int bid = blockIdx.x;
    int b = bid & 7, rest = bid >> 3;
    int y = rest & 63, cg = rest >> 6;   // cg: 64-channel group
    int t = threadIdx.x;
    __shared__ float tile[64][65];
    int xcol = t & 63;
    int crow = t >> 6;  // 0..3
    const float* xb = x + ((size_t)(b * Cc + cg * 64) * Nn) + y * 64;
#pragma unroll
    for (int i = 0; i < 16; i++) {
        int c = crow + i * 4;
        tile[c][xcol] = xb[(size_t)c * Nn + xcol];
    }
    __syncthreads();
    int c = t & 63;
    int x4 = t >> 6;
    ushort* dst = xpad + (((size_t)(b * HP + (y + 1)) * HP) + 1) * Cc + cg * 64 + c;
#pragma unroll
    for (int i = 0; i < 16; i++) {
        int xx = x4 + i * 4;
        dst[(size_t)xx * Cc] = f2bf(tile[c][xx]);
    }
}

// ---------------------------------------------------------------------------
// K2: repack weights w[oc][c][3][3] (f32) -> wt[r][oc][c] (bf16), r = dy*3+dx
__global__ __launch_bounds__(256) void repack_w(const float* __restrict__ kw,
                                                const float* __restrict__ vw,
                                                ushort* __restrict__ wtk,
                                                ushort* __restrict__ wtv) {
    int idx = blockIdx.x * 256 + threadIdx.x;
    const int nk = KD * Cc;   // 32768
    const int nv = VD * Cc;   // 65536
    if (idx < nk) {
        const float* src = kw + (size_t)idx * 9;
        int oc = idx / Cc, c = idx % Cc;
#pragma unroll
        for (int r = 0; r < 9; r++) wtk[((size_t)r * KD + oc) * Cc + c] = f2bf(src[r]);
    } else if (idx < nk + nv) {
        int j = idx - nk;
        const float* src = vw + (size_t)j * 9;
        int oc = j / Cc, c = j % Cc;
#pragma unroll
        for (int r = 0; r < 9; r++) wtv[((size_t)r * VD + oc) * Cc + c] = f2bf(src[r]);
    }
}

// ---------------------------------------------------------------------------
// K3a: key conv (OC=128), ONE row/block (512 blocks -> 2/CU), weight slab
// LDS-staged (r6-proven). Epilogue FUSES sq: block owns all 128 oc per
// position, so sq2 = kScale * sum(bf16(kt)^2) is 2 shfl_xors away. This
// removes the separate sq_kernel and its Kt re-read.
__global__ __launch_bounds__(256) void conv_k(const ushort* __restrict__ xpad,
                                              const ushort* __restrict__ wt,
                                              const float* __restrict__ bias,
                                              ushort* __restrict__ kt_out,
                                              float* __restrict__ sq_out) {
    int bid = blockIdx.x;
    int b = bid & 7, y = bid >> 3;
    int lane = threadIdx.x & 63, wv = threadIdx.x >> 6;
    int l15 = lane & 15, g = lane >> 4;
    const int swzA = l15 & 7;

    __shared__ ushort wslab[2][128 * 128];   // 2 x 32KB weight half-slabs

    size_t wsoff[8];
    int ldsrow[8];
#pragma unroll
    for (int h = 0; h < 8; h++) {
        int row = wv * 32 + h * 4 + (lane >> 4);      // oc row this lane stages
        wsoff[h] = (size_t)row * Cc + (((lane & 15) ^ (row & 7)) * 8);
        ldsrow[h] = (wv * 32 + h * 4) * 128;
    }

    floatx4 acc[8];
#pragma unroll
    for (int m = 0; m < 8; m++) acc[m] = (floatx4){0.f, 0.f, 0.f, 0.f};

    const ushort* xb = xpad + ((size_t)b * HP * HP) * Cc;
    int xcol = wv * 16 + l15;  // output x position (wave's 16 columns)

    auto stage = [&](int hs, int bi) {
        int r = hs >> 1, hc = hs & 1;
        const ushort* wb = wt + ((size_t)r * KD) * Cc + hc * 128;
#pragma unroll
        for (int h = 0; h < 8; h++)
            gload_lds16(wb + wsoff[h], &wslab[bi][ldsrow[h]]);
    };

    stage(0, 0);
    __syncthreads();   // implicit vmcnt(0): slab 0 resident

#pragma unroll 1
    for (int hs = 0; hs < 18; ++hs) {
        int bi = hs & 1;
        if (hs < 17) stage(hs + 1, bi ^ 1);   // prefetch; drained by end barrier

        int r = hs >> 1, hc = hs & 1;
        int dy = r / 3, dx = r % 3;
        const ushort* bsrc = xb + ((size_t)(y + dy) * HP + xcol + dx) * Cc + hc * 128 + g * 8;
#pragma unroll
        for (int cc = 0; cc < 4; cc++) {      // 4 k-steps of 32 channels
            short8_t bfrag = *(const short8_t*)(bsrc + cc * 32);
#pragma unroll
            for (int m = 0; m < 8; m++) {
                short8_t afrag = *(const short8_t*)&wslab[bi][(m * 16 + l15) * 128 + ((cc * 4 + g) ^ swzA) * 8];
                acc[m] = __builtin_amdgcn_mfma_f32_16x16x32_bf16(afrag, bfrag, acc[m], 0, 0, 0);
            }
        }
        __syncthreads();   // reads done + prefetch drained
    }

    int pos = y * 64 + xcol;
    ushort* kt = kt_out + ((size_t)(b * Nn + pos)) * KD;
    float ssum = 0.f;
#pragma unroll
    for (int m = 0; m < 8; m++) {
        floatx4 bv = *(const floatx4*)(bias + m * 16 + g * 4);
        shortx4 pk;
#pragma unroll
        for (int r = 0; r < 4; r++) {
            pk[r] = (short)f2bf(acc[m][r] + bv[r]);
            float q = bf2f((ushort)pk[r]);   // bf16-rounded value (diag-exact sq)
            ssum += q * q;
        }
        *(shortx4*)(kt + m * 16 + g * 4) = pk;
    }
    // lanes {l15, +16, +32, +48} hold the 4 oc-slices of this position
    ssum += __shfl_xor(ssum, 16, 64);
    ssum += __shfl_xor(ssum, 32, 64);
    if (g == 0) sq_out[b * Nn + pos] = ssum * kScale;
}

// ---------------------------------------------------------------------------
// K3b: value conv (OC=256), TWO rows/block (512 blocks -> 2/CU residency
// kept): each staged afr read feeds 2 MFMAs -> slab LDS reads per unit work
// halved. Writes d_out ch 0..255 (f32) + Vb bf16 copy.
__global__ __launch_bounds__(256) void conv_v(const ushort* __restrict__ xpad,
                                              const ushort* __restrict__ wt,
                                              const float* __restrict__ bias,
                                              float* __restrict__ f32_out,
                                              ushort* __restrict__ vb_out) {
    int bid = blockIdx.x;
    int b = bid & 7;
    int ocg = (bid >> 3) & 1;
    int y0 = (bid >> 4) * 2;
    int lane = threadIdx.x & 63, wv = threadIdx.x >> 6;
    int l15 = lane & 15, g = lane >> 4;
    int oc0 = ocg * 128;
    const int swzA = l15 & 7;

    __shared__ ushort wslab[2][128 * 128];   // 2 x 32KB weight half-slabs

    size_t wsoff[8];
    int ldsrow[8];
#pragma unroll
    for (int h = 0; h < 8; h++) {
        int row = wv * 32 + h * 4 + (lane >> 4);      // oc row this lane stages
        wsoff[h] = (size_t)row * Cc + (((lane & 15) ^ (row & 7)) * 8);
        ldsrow[h] = (wv * 32 + h * 4) * 128;
    }

    floatx4 acc[8][2];
#pragma unroll
    for (int m = 0; m < 8; m++)
#pragma unroll
        for (int rr = 0; rr < 2; rr++) acc[m][rr] = (floatx4){0.f, 0.f, 0.f, 0.f};

    const ushort* xb = xpad + ((size_t)b * HP * HP) * Cc;
    int xcol = wv * 16 + l15;  // output x position (wave's 16 columns)

    auto stage = [&](int hs, int bi) {
        int r = hs >> 1, hc = hs & 1;
        const ushort* wb = wt + ((size_t)r * VD + oc0) * Cc + hc * 128;
#pragma unroll
        for (int h = 0; h < 8; h++)
            gload_lds16(wb + wsoff[h], &wslab[bi][ldsrow[h]]);
    };

    stage(0, 0);
    __syncthreads();   // implicit vmcnt(0): slab 0 resident

#pragma unroll 1
    for (int hs = 0; hs < 18; ++hs) {
        int bi = hs & 1;
        if (hs < 17) stage(hs + 1, bi ^ 1);   // prefetch; drained by end barrier

        int r = hs >> 1, hc = hs & 1;
        int dy = r / 3, dx = r % 3;
        const ushort* bsrc0 = xb + ((size_t)(y0 + dy) * HP + xcol + dx) * Cc + hc * 128 + g * 8;
        const ushort* bsrc1 = bsrc0 + (size_t)HP * Cc;   // row y0+1
#pragma unroll
        for (int cc = 0; cc < 4; cc++) {      // 4 k-steps of 32 channels
            short8_t bfragA = *(const short8_t*)(bsrc0 + cc * 32);
            short8_t bfragB = *(const short8_t*)(bsrc1 + cc * 32);
#pragma unroll
            for (int m = 0; m < 8; m++) {
                short8_t afrag = *(const short8_t*)&wslab[bi][(m * 16 + l15) * 128 + ((cc * 4 + g) ^ swzA) * 8];
                acc[m][0] = __builtin_amdgcn_mfma_f32_16x16x32_bf16(afrag, bfragA, acc[m][0], 0, 0, 0);
                acc[m][1] = __builtin_amdgcn_mfma_f32_16x16x32_bf16(afrag, bfragB, acc[m][1], 0, 0, 0);
            }
        }
        __syncthreads();   // reads done + prefetch drained
    }

#pragma unroll
    for (int rr = 0; rr < 2; rr++) {
        int pos = (y0 + rr) * 64 + xcol;
#pragma unroll
        for (int m = 0; m < 8; m++) {
            floatx4 bv = *(const floatx4*)(bias + oc0 + m * 16 + g * 4);
#pragma unroll
            for (int r = 0; r < 4; r++) {
                int oc = oc0 + m * 16 + g * 4 + r;
                float v = acc[m][rr][r] + bv[r];
                f32_out[((size_t)(b * 512 + oc)) * Nn + pos] = v;       // d_out f32
                vb_out[((size_t)(b * VD + oc)) * Nn + pos] = f2bf(v);   // bf16 for PV
            }
        }
    }
}

// ---------------------------------------------------------------------------
// K5: fused attention — EXACT round-12 structure (best measured: 145.6us).
// i-tile 64, j=16/wave S-phase with per-wave pt, PV split vd-half x j-half,
// single-buffered K/V, 2 barriers/iter, proven 2-way swizzles, lean transform.
__global__ __launch_bounds__(256) void attn_kernel(const ushort* __restrict__ kt,
                                                   const ushort* __restrict__ vb,
                                                   const float* __restrict__ sq2,
                                                   float* __restrict__ out) {
    int bid = blockIdx.x;
    int b = bid & 7, jt = bid >> 3;
    int lane = threadIdx.x & 63, wv = threadIdx.x >> 6;
    int l15 = lane & 15, g = lane >> 4;

    __shared__ ushort bufK[64 * 128];      // 16KB: [i-row][swizzled 16B units]
    __shared__ ushort bufV[256 * 64];      // 32KB: [vd][swizzled 16B units]
    __shared__ ushort pt[4][16][72];       // 9KB: per-wave P^T tile [j][i]
    __shared__ float dls[4][16];           // 256B: per-wave dsum exchange

    const ushort* ktb = kt + ((size_t)b * Nn) * KD;
    const ushort* vbb = vb + ((size_t)b * VD) * Nn;
    const float* sqb = sq2 + b * Nn;

    // per-lane staging source pointers (it=0); LDS dests are wave-uniform
    const ushort* skp[4];
#pragma unroll
    for (int h = 0; h < 4; h++) {
        int row = wv * 16 + h * 4 + (lane >> 4);
        skp[h] = ktb + (size_t)row * KD + (((lane & 15) ^ (row & 7)) * 8);
    }
    const ushort* svp[8];
#pragma unroll
    for (int h = 0; h < 8; h++) {
        int vd = wv * 64 + h * 8 + (lane >> 3);
        svp[h] = vbb + (size_t)vd * Nn + (((lane & 7) ^ (vd & 7)) * 8);
    }

    // kj B-frags for this wave's 16 j columns (S-phase ownership)
    int j = jt * 64 + wv * 16 + l15;
    short8_t kj[4];
#pragma unroll
    for (int kk = 0; kk < 4; kk++)
        kj[kk] = *(const short8_t*)(ktb + (size_t)j * KD + kk * 32 + g * 8);

    // PV ownership: vd-half vh = wv>>1, j-half jh = wv&1
    const int vh = wv >> 1, jh = wv & 1;

    floatx4 acc[8][2];   // [m: vd-tile within half][s: j-sub within half]
#pragma unroll
    for (int m = 0; m < 8; m++)
#pragma unroll
        for (int s = 0; s < 2; s++) acc[m][s] = (floatx4){0.f, 0.f, 0.f, 0.f};
    float dsum = 0.f;
    const int swzA = l15 & 7;

    // prologue: stage K(0), V(0)
#pragma unroll
    for (int h = 0; h < 4; h++) gload_lds16(skp[h], &bufK[(wv * 16 + h * 4) * 128]);
#pragma unroll
    for (int h = 0; h < 8; h++) gload_lds16(svp[h], &bufV[(wv * 64 + h * 8) * 64]);
    __syncthreads();   // implicit vmcnt(0): both tiles resident

#pragma unroll 1
    for (int it = 0; it < 64; ++it) {
        int i0 = it * 64;

        // S-phase: A-frags from LDS K tile
        floatx4 sacc[4];
#pragma unroll
        for (int f = 0; f < 4; f++) sacc[f] = (floatx4){0.f, 0.f, 0.f, 0.f};
#pragma unroll
        for (int kk = 0; kk < 4; kk++) {
#pragma unroll
            for (int f = 0; f < 4; f++) {
                short8_t afr = *(const short8_t*)&bufK[(f * 16 + l15) * 128 + ((kk * 4 + g) ^ swzA) * 8];
                sacc[f] = __builtin_amdgcn_mfma_f32_16x16x32_bf16(afr, kj[kk], sacc[f], 0, 0, 0);
            }
        }
        // P' = exp2(TwoK*dot - sq2i); pack bf16 pairs; write per-wave P^T
#pragma unroll
        for (int f = 0; f < 4; f++) {
            floatx4 sqi = *(const floatx4*)(sqb + i0 + f * 16 + g * 4);
            float p0 = exp2_raw(sacc[f][0] * kTwoK - sqi[0]);
            float p1 = exp2_raw(sacc[f][1] * kTwoK - sqi[1]);
            float p2 = exp2_raw(sacc[f][2] * kTwoK - sqi[2]);
            float p3 = exp2_raw(sacc[f][3] * kTwoK - sqi[3]);
            dsum += (p0 + p1) + (p2 + p3);
            uint2 w2 = {pk_bf16(p0, p1), pk_bf16(p2, p3)};
            *(uint2*)&pt[wv][l15][f * 16 + g * 4] = w2;
        }
        __syncthreads();   // sync1: ALL pt slices visible; bufK reads done

        // issue K(it+1) prefetch (WAR-safe; drained by sync2's implicit vmcnt0)
        if (it < 63) {
#pragma unroll
            for (int h = 0; h < 4; h++)
                gload_lds16(skp[h] + (size_t)(i0 + 64) * KD, &bufK[(wv * 16 + h * 4) * 128]);
        }

        // PV (split): wave handles vd in [vh*128, vh*128+128), j-subs of half jh
#pragma unroll
        for (int k2 = 0; k2 < 2; k2++) {
            short8_t pfr[2];
#pragma unroll
            for (int s = 0; s < 2; s++)
                pfr[s] = *(const short8_t*)&pt[jh * 2 + s][l15][k2 * 32 + g * 8];
#pragma unroll
            for (int m = 0; m < 8; m++) {
                int row = vh * 128 + m * 16 + l15;
                short8_t vfr = *(const short8_t*)&bufV[row * 64 + ((k2 * 4 + g) ^ swzA) * 8];
#pragma unroll
                for (int s = 0; s < 2; s++)
                    acc[m][s] = __builtin_amdgcn_mfma_f32_16x16x32_bf16(vfr, pfr[s], acc[m][s], 0, 0, 0);
            }
        }
        __syncthreads();   // sync2: bufV/pt reads done; K prefetch drained

        // issue V(it+1) prefetch (drained at next iter's sync1)
        if (it < 63) {
#pragma unroll
            for (int h = 0; h < 8; h++)
                gload_lds16(svp[h] + (i0 + 64), &bufV[(wv * 64 + h * 8) * 64]);
        }
    }

    // dsum for this wave's S-columns (j = wv*16 + l15): reduce across g-slices
    dsum += __shfl_xor(dsum, 16, 64);
    dsum += __shfl_xor(dsum, 32, 64);
    if (g == 0) dls[wv][l15] = dsum;
    __syncthreads();
    float rden[2];
#pragma unroll
    for (int s = 0; s < 2; s++) rden[s] = 1.f / dls[jh * 2 + s][l15];

    // output: vd = vh*128 + m*16 + g*4 + r, j = jt*64 + jh*32 + s*16 + l15
    float* ob = out + ((size_t)(b * 512 + 256 + vh * 128)) * Nn + jt * 64 + jh * 32 + l15;
#pragma unroll
    for (int m = 0; m < 8; m++) {
#pragma unroll
        for (int s = 0; s < 2; s++) {
#pragma unroll
            for (int r = 0; r < 4; r++) {
                int vd = m * 16 + g * 4 + r;
                ob[(size_t)vd * Nn + s * 16] = acc[m][s][r] * rden[s];
            }
        }
    }
}

// ---------------------------------------------------------------------------
extern "C" void kernel_launch(void* const* d_in, const int* in_sizes, int n_in,
                              void* d_out, int out_size, void* d_ws, size_t ws_size,
                              hipStream_t stream) {
    const float* x     = (const float*)d_in[0];
    const float* kw    = (const float*)d_in[1];
    const float* kbias = (const float*)d_in[2];
    const float* vw    = (const float*)d_in[3];
    const float* vbias = (const float*)d_in[4];
    float* out = (float*)d_out;  // reference output dtype is FLOAT32
    char* ws = (char*)d_ws;

    // workspace layout (bytes) — total 44,908,544
    constexpr size_t XPAD = 0;                         // 8*66*66*256*2 = 17,842,176
    constexpr size_t WTK  = 17842176;                  // 9*128*256*2   =    589,824
    constexpr size_t WTV  = 18432000;                  // 9*256*256*2   =  1,179,648
    constexpr size_t KT   = 19611648;                  // 8*4096*128*2  =  8,388,608
    constexpr size_t VB   = 28000256;                  // 8*256*4096*2  = 16,777,216
    constexpr size_t SQ   = 44777472;                  // 8*4096*4      =    131,072

    ushort* xpad = (ushort*)(ws + XPAD);
    ushort* wtk  = (ushort*)(ws + WTK);
    ushort* wtv  = (ushort*)(ws + WTV);
    ushort* ktw  = (ushort*)(ws + KT);
    ushort* vbw  = (ushort*)(ws + VB);
    float*  sqw  = (float*)(ws + SQ);

    hipMemsetAsync(xpad, 0, 17842176, stream);  // zero borders of padded input
    pad_transpose<<<dim3(2048), 256, 0, stream>>>(x, xpad);
    repack_w<<<dim3(384), 256, 0, stream>>>(kw, vw, wtk, wtv);
    conv_k<<<dim3(512), 256, 0, stream>>>(xpad, wtk, kbias, ktw, sqw);
    conv_v<<<dim3(512), 256, 0, stream>>>(xpad, wtv, vbias, out, vbw);
    attn_kernel<<<dim3(512), 256, 0, stream>>>(ktw, vbw, sqw, out);
}